// Round 16
// baseline (331.769 us; speedup 1.0000x reference)
//
#include <hip/hip_runtime.h>
#include <hip/hip_bf16.h>

#define NN 50000
#define NE 600000
#define DD 128
#define RR 8
#define KY 1152   /* Y cols: 8 relations * 128 + root 128 */

#define N2 (NN * RR)                       /* (v,r) segments, v-major */
#define SCHUNK 1024
#define NBS2 ((N2 + SCHUNK - 1) / SCHUNK)  /* 391 */
#define MGRID ((NN + 127) / 128)           /* 391 row-tiles */

typedef __attribute__((ext_vector_type(8))) short short8;
typedef __attribute__((ext_vector_type(4))) float f32x4;
typedef __attribute__((ext_vector_type(4))) unsigned uint4v;

__device__ __forceinline__ unsigned short f2b(float x){
  __hip_bfloat16 h = __float2bfloat16(x);
  return __builtin_bit_cast(unsigned short, h);
}
__device__ __forceinline__ float blo(unsigned u){ return __builtin_bit_cast(float, u << 16); }
__device__ __forceinline__ float bhi(unsigned u){ return __builtin_bit_cast(float, u & 0xFFFF0000u); }
__device__ __forceinline__ unsigned pack2(float a, float b){
  return (unsigned)f2b(a) | ((unsigned)f2b(b) << 16);
}

#define GLDS16(g, l) __builtin_amdgcn_global_load_lds( \
    (const __attribute__((address_space(1))) void*)(g), \
    (__attribute__((address_space(3))) void*)(l), 16, 0, 0)

// ---------------- edge structure build: CSR over v-major (dst, rel) segments ----------------
// also builds omask[v] bit r = "v has >=1 OUT-edge of relation r" (Y-chunk liveness)
__global__ __launch_bounds__(256) void k_hist(const int* __restrict__ ei,
                                              const int* __restrict__ et,
                                              int* __restrict__ cnt,
                                              unsigned* __restrict__ omask) {
  int e = blockIdx.x * 256 + threadIdx.x;
  if (e < NE) {
    int src = ei[e];
    int dst = ei[NE + e];
    int r = et[e];
    atomicAdd(&cnt[dst * RR + r], 1);
    atomicOr(&omask[src], 1u << r);
  }
}

__global__ __launch_bounds__(256) void k_scan1(const int* __restrict__ cnt,
                                               int* __restrict__ bsum) {
  int b = blockIdx.x, t = threadIdx.x;
  int base = b * SCHUNK + t * 4;
  int s = 0;
  if (base < N2) {
    int4 v = *(const int4*)&cnt[base];
    s = v.x + v.y + v.z + v.w;
  }
  #pragma unroll
  for (int off = 32; off; off >>= 1) s += __shfl_down(s, off);
  __shared__ int wsum[4];
  int lane = t & 63, wv = t >> 6;
  if (lane == 0) wsum[wv] = s;
  __syncthreads();
  if (t == 0) bsum[b] = wsum[0] + wsum[1] + wsum[2] + wsum[3];
}

__global__ __launch_bounds__(512) void k_scan2(const int* __restrict__ bsum,
                                               int* __restrict__ boff) {
  int t = threadIdx.x, lane = t & 63, wv = t >> 6;
  int v = (t < NBS2) ? bsum[t] : 0;
  int x = v;
  #pragma unroll
  for (int off = 1; off < 64; off <<= 1) {
    int y = __shfl_up(x, off);
    if (lane >= off) x += y;
  }
  __shared__ int wt[8];
  if (lane == 63) wt[wv] = x;
  __syncthreads();
  int woff = 0;
  for (int w = 0; w < wv; w++) woff += wt[w];
  if (t < NBS2) boff[t] = woff + x - v;
}

__global__ __launch_bounds__(256) void k_scan3(const int* __restrict__ cnt,
                                               const int* __restrict__ boff,
                                               int* __restrict__ rp2,
                                               int* __restrict__ cur2) {
  int b = blockIdx.x, t = threadIdx.x;
  int lane = t & 63, wv = t >> 6;
  int base = b * SCHUNK + t * 4;
  int v[4] = {0, 0, 0, 0};
  int s = 0;
  if (base < N2) {
    int4 q = *(const int4*)&cnt[base];
    v[0] = q.x; v[1] = q.y; v[2] = q.z; v[3] = q.w;
    s = q.x + q.y + q.z + q.w;
  }
  int x = s;
  #pragma unroll
  for (int off = 1; off < 64; off <<= 1) {
    int y = __shfl_up(x, off);
    if (lane >= off) x += y;
  }
  __shared__ int wtot[4];
  if (lane == 63) wtot[wv] = x;
  __syncthreads();
  int woff = 0;
  for (int w = 0; w < wv; w++) woff += wtot[w];
  int exc = boff[b] + woff + x - s;
  if (base < N2) {
    #pragma unroll
    for (int j = 0; j < 4; j++) {
      cur2[base + j] = exc;
      rp2[base + j + 1] = exc + v[j];
      exc += v[j];
    }
  }
  if (b == 0 && t == 0) rp2[0] = 0;
}

__global__ __launch_bounds__(256) void k_scatter(const int* __restrict__ ei,
                                                 const int* __restrict__ et,
                                                 int* __restrict__ cur2,
                                                 unsigned* __restrict__ packed) {
  int e = blockIdx.x * 256 + threadIdx.x;
  if (e < NE) {
    int src = ei[e];
    int dst = ei[NE + e];
    int r = et[e];
    int p = atomicAdd(&cur2[dst * RR + r], 1);
    packed[p] = (unsigned)src | ((unsigned)r << 16);   // src < 65536
  }
}

// ---------------- prep: bf16 conversions ----------------
__global__ __launch_bounds__(256) void k_xb(const float* __restrict__ x,
                                            unsigned* __restrict__ xb2) {
  int i = blockIdx.x * 256 + threadIdx.x;
  if (i < NN * (DD / 2)) {
    float2 v = ((const float2*)x)[i];
    xb2[i] = pack2(v.x, v.y);
  }
}

// WT2[l][j][k] bf16, j in [0,1152): j<1024 -> rel_w[l][j>>7][k][j&127], else root_w[l][k][j-1024]
__global__ __launch_bounds__(256) void k_wt2(const float* __restrict__ rel_w,
                                             const float* __restrict__ root_w,
                                             unsigned short* __restrict__ WT2) {
  int idx = blockIdx.x * 256 + threadIdx.x;
  if (idx >= 2 * KY * DD) return;
  int k = idx % DD;
  int j = (idx / DD) % KY;
  int l = idx / (DD * KY);
  float v;
  if (j < RR * DD) v = rel_w[(((size_t)l * RR + (j >> 7)) * DD + k) * DD + (j & 127)];
  else             v = root_w[((size_t)l * DD + k) * DD + (j - RR * DD)];
  WT2[idx] = f2b(v);
}

// PT[n][k] = proj_w[k][n], k<256
__global__ __launch_bounds__(256) void k_pt(const float* __restrict__ proj_w,
                                            unsigned short* __restrict__ PT) {
  int idx = blockIdx.x * 256 + threadIdx.x;
  if (idx >= DD * 256) return;
  int k = idx % 256;
  int n = idx / 256;
  PT[idx] = f2b(proj_w[(size_t)k * DD + n]);
}

// ---------------- Y-GEMM v11: Y[M,1152] = A[M,128] @ W'[128,1152]  (bf16 out) ----------------
// v6 (round-10/12 best: 512 thr, A-only LDS, B regs after barrier, direct u16
// stores, 1 barrier) + DEAD-CHUNK STORE ELIMINATION: Y[v, ct*128:] is only
// read by aggD if v has an out-edge of relation ct (omask bit). ~22% of
// relation chunks are dead -> skip their stores. Root chunk (ct==8) always live.
__global__ __launch_bounds__(512) void k_ygemm(const unsigned short* __restrict__ A, int lda,
                                               const unsigned short* __restrict__ B2, /* [1152][128] */
                                               const unsigned* __restrict__ omask,
                                               unsigned short* __restrict__ Y) {
  __shared__ unsigned short smA[128 * 128];   // 32 KB
  int t = threadIdx.x;
  // bijective XCD-grouped mapping (grid = MGRID*9 = 3519)
  const int nb = MGRID * 9, q8 = nb >> 3, r8 = nb & 7;   // 3519, 439, 7
  int xcd = blockIdx.x & 7, idx = blockIdx.x >> 3;
  int w = (xcd < r8 ? xcd * (q8 + 1) : r8 * (q8 + 1) + (xcd - r8) * q8) + idx;
  int rt = w / 9, ct = w % 9;

  int lane = t & 63, wv = t >> 6;             // wv 0..7
  int wm = wv >> 2, wn = wv & 3;              // 2M x 4N wave grid, 64x32 each
  int l15 = lane & 15, lk = lane >> 4;

  // issue A-stage (swizzled source -> linear LDS); nothing else before barrier
  #pragma unroll
  for (int i = 0; i < 4; i++) {
    int f = i * 512 + t;
    int row = f >> 4, cl = f & 15;
    int cg = cl ^ (row & 15);
    int rg = rt * 128 + row; if (rg >= NN) rg = NN - 1;
    GLDS16(A + (size_t)rg * lda + cg * 8, &smA[f * 8]);
  }
  __syncthreads();   // A tile ready

  // B fragments direct from L2 (0.29 MB, hot on this XCD)
  short8 bf[4][2];
  #pragma unroll
  for (int kk = 0; kk < 4; kk++)
    #pragma unroll
    for (int q = 0; q < 2; q++) {
      int rb = ct * 128 + wn * 32 + q * 16 + l15;
      bf[kk][q] = *(const short8*)(B2 + (size_t)rb * DD + (kk * 4 + lk) * 8);
    }

  f32x4 acc[4][2];
  #pragma unroll
  for (int mi = 0; mi < 4; mi++)
    #pragma unroll
    for (int ni = 0; ni < 2; ni++)
      acc[mi][ni] = (f32x4){0.f, 0.f, 0.f, 0.f};

  #pragma unroll
  for (int kk = 0; kk < 4; kk++) {
    short8 af[4];
    int c = kk * 4 + lk;
    #pragma unroll
    for (int q = 0; q < 4; q++) {
      int r = wm * 64 + q * 16 + l15;
      af[q] = *(const short8*)&smA[r * 128 + ((c ^ (r & 15)) << 3)];
    }
    #pragma unroll
    for (int mi = 0; mi < 4; mi++)
      #pragma unroll
      for (int ni = 0; ni < 2; ni++)
        acc[mi][ni] = __builtin_amdgcn_mfma_f32_16x16x32_bf16(af[mi], bf[kk][ni], acc[mi][ni], 0, 0, 0);
  }

  // direct store with liveness predicate: quarter-wave-uniform omask loads
  #pragma unroll
  for (int mi = 0; mi < 4; mi++) {
    #pragma unroll
    for (int ni = 0; ni < 2; ni++) {
      int col = ct * 128 + wn * 32 + ni * 16 + l15;
      #pragma unroll
      for (int j = 0; j < 4; j++) {
        int rg = rt * 128 + wm * 64 + mi * 16 + lk * 4 + j;
        if (rg < NN) {
          bool live = (ct == 8) || ((omask[rg] >> ct) & 1u);
          if (live) Y[(size_t)rg * KY + col] = f2b(acc[mi][ni][j]);
        }
      }
    }
  }
}

// ---------------- weighted gather: out[v] = sum_e w_e * Y[src_e, r_e*128:] + Y[v,1024:] + bias ----------------
__global__ __launch_bounds__(256) void k_aggD(const unsigned short* __restrict__ Y,
                                              const unsigned* __restrict__ packed,
                                              const int* __restrict__ rp2,
                                              const float* __restrict__ bias,
                                              float* __restrict__ outf,
                                              unsigned short* __restrict__ hb, int hboff) {
  int v = blockIdx.x * 4 + (threadIdx.x >> 6);
  int lane = threadIdx.x & 63;
  int q = lane >> 4, sub = lane & 15;

  // fenceposts rp2[v*8 .. v*8+8] on lanes 0..8
  int f = 0;
  if (lane <= 8) f = rp2[v * RR + lane];
  int fn = __shfl(f, lane + 1);             // lane l: rp2[v*8+l+1] (l<8 valid)
  int c = fn - f;
  float winv = (lane < 8 && c > 0) ? 1.f / (float)c : 0.f;
  int e0 = __shfl(f, 0), e1 = __shfl(f, 8);

  float acc[8];
  #pragma unroll
  for (int j = 0; j < 8; j++) acc[j] = 0.f;

  // 4 quarter-waves, each owns 16B of the row; 2-deep pipeline on packed[]
  int e = e0 + q;
  unsigned rec = (e < e1) ? packed[e] : 0u;
  while (e < e1) {
    int en = e + 4;
    unsigned rec_next = (en < e1) ? packed[en] : 0u;
    int src = rec & 0xFFFF;
    int r = rec >> 16;
    float w = __shfl(winv, r);
    uint4v u = *(const uint4v*)(Y + (size_t)src * KY + r * DD + sub * 8);
    #pragma unroll
    for (int i = 0; i < 4; i++) {
      acc[2 * i]     += w * blo(u[i]);
      acc[2 * i + 1] += w * bhi(u[i]);
    }
    e = en; rec = rec_next;
  }

  // root term (once, quarter 0)
  if (q == 0) {
    uint4v u = *(const uint4v*)(Y + (size_t)v * KY + RR * DD + sub * 8);
    #pragma unroll
    for (int i = 0; i < 4; i++) {
      acc[2 * i]     += blo(u[i]);
      acc[2 * i + 1] += bhi(u[i]);
    }
  }

  // reduce across quarters
  #pragma unroll
  for (int j = 0; j < 8; j++) {
    acc[j] += __shfl_xor(acc[j], 32);
    acc[j] += __shfl_xor(acc[j], 16);
  }

  if (q == 0) {
    float4 b0 = *(const float4*)&bias[sub * 8];
    float4 b1 = *(const float4*)&bias[sub * 8 + 4];
    float val[8];
    val[0] = fmaxf(acc[0] + b0.x, 0.f); val[1] = fmaxf(acc[1] + b0.y, 0.f);
    val[2] = fmaxf(acc[2] + b0.z, 0.f); val[3] = fmaxf(acc[3] + b0.w, 0.f);
    val[4] = fmaxf(acc[4] + b1.x, 0.f); val[5] = fmaxf(acc[5] + b1.y, 0.f);
    val[6] = fmaxf(acc[6] + b1.z, 0.f); val[7] = fmaxf(acc[7] + b1.w, 0.f);
    float4* of = (float4*)&outf[(size_t)v * DD + sub * 8];
    of[0] = (float4){val[0], val[1], val[2], val[3]};
    of[1] = (float4){val[4], val[5], val[6], val[7]};
    uint4v hv;
    #pragma unroll
    for (int i = 0; i < 4; i++) hv[i] = pack2(val[2 * i], val[2 * i + 1]);
    *(uint4v*)(hb + (size_t)v * 256 + hboff + sub * 8) = hv;
  }
}

// ---------------- bf16 MFMA GEMM (projection): C[M,128] = A[M,K] * BT[128,K]^T + bias ----------------
__global__ __launch_bounds__(256) void k_gemm(const unsigned short* __restrict__ A, int lda,
                                              const unsigned short* __restrict__ BT, int ldb,
                                              int M, int K,
                                              const float* __restrict__ bias,
                                              float* __restrict__ outf) {
  __shared__ unsigned short sA[128 * 64];
  __shared__ unsigned short sB[128 * 64];
  int t = threadIdx.x;
  int bm = blockIdx.x;
  int lane = t & 63, wv = t >> 6;
  int wm = wv >> 1, wn = wv & 1;
  int l15 = lane & 15, lk = lane >> 4;

  f32x4 acc[4][4];
  #pragma unroll
  for (int mi = 0; mi < 4; mi++)
    #pragma unroll
    for (int ni = 0; ni < 4; ni++)
      acc[mi][ni] = (f32x4){0.f, 0.f, 0.f, 0.f};

  int nkt = K >> 6;
  for (int kt = 0; kt < nkt; kt++) {
    #pragma unroll
    for (int i = 0; i < 4; i++) {
      int f = i * 256 + t;
      int row = f >> 3, cl = f & 7;
      int cg = cl ^ (row & 7);
      int rg = bm * 128 + row;
      if (rg >= M) rg = M - 1;
      GLDS16(A + (size_t)rg * lda + kt * 64 + cg * 8, &sA[f * 8]);
    }
    #pragma unroll
    for (int i = 0; i < 4; i++) {
      int f = i * 256 + t;
      int row = f >> 3, cl = f & 7;
      int cg = cl ^ (row & 7);
      GLDS16(BT + (size_t)row * ldb + kt * 64 + cg * 8, &sB[f * 8]);
    }
    __syncthreads();

    short8 af[4][2], bf[4][2];
    #pragma unroll
    for (int mi = 0; mi < 4; mi++) {
      #pragma unroll
      for (int kk = 0; kk < 2; kk++) {
        int r = wm * 64 + mi * 16 + l15;
        int c = kk * 4 + lk;
        af[mi][kk] = *(const short8*)&sA[((r << 3) + (c ^ (r & 7))) << 3];
        int rb = wn * 64 + mi * 16 + l15;
        bf[mi][kk] = *(const short8*)&sB[((rb << 3) + (c ^ (rb & 7))) << 3];
      }
    }
    #pragma unroll
    for (int mi = 0; mi < 4; mi++)
      #pragma unroll
      for (int ni = 0; ni < 4; ni++)
        #pragma unroll
        for (int kk = 0; kk < 2; kk++)
          acc[mi][ni] = __builtin_amdgcn_mfma_f32_16x16x32_bf16(af[mi][kk], bf[ni][kk], acc[mi][ni], 0, 0, 0);
    __syncthreads();
  }

  #pragma unroll
  for (int mi = 0; mi < 4; mi++) {
    #pragma unroll
    for (int ni = 0; ni < 4; ni++) {
      int cg = wn * 64 + ni * 16 + l15;
      float bv = bias[cg];
      #pragma unroll
      for (int j = 0; j < 4; j++) {
        int rg = bm * 128 + wm * 64 + mi * 16 + lk * 4 + j;
        if (rg < M) outf[(size_t)rg * 128 + cg] = acc[mi][ni][j] + bv;
      }
    }
  }
}

// ---------------- launch ----------------
extern "C" void kernel_launch(void* const* d_in, const int* in_sizes, int n_in,
                              void* d_out, int out_size, void* d_ws, size_t ws_size,
                              hipStream_t stream) {
  const float* node_feat = (const float*)d_in[0];
  const int*   ei        = (const int*)d_in[1];
  const int*   et        = (const int*)d_in[2];
  const float* rel_w     = (const float*)d_in[3];
  const float* root_w    = (const float*)d_in[4];
  const float* bias      = (const float*)d_in[5];
  const float* proj_w    = (const float*)d_in[6];
  const float* proj_b    = (const float*)d_in[7];
  float* out = (float*)d_out;

  char* ws = (char*)d_ws;
  size_t off = 0;
  auto carve = [&](size_t bytes) { void* p = ws + off; off = (off + bytes + 255) & ~(size_t)255; return p; };
  unsigned short* Y    = (unsigned short*)carve((size_t)NN * KY * 2);      // 115.2 MB
  unsigned short* Hb   = (unsigned short*)carve((size_t)NN * 256 * 2);     // 25.6 MB [h1|h2] bf16
  unsigned short* xb   = (unsigned short*)carve((size_t)NN * DD * 2);      // 12.8 MB
  unsigned short* WT2  = (unsigned short*)carve((size_t)2 * KY * DD * 2);  // 0.59 MB
  unsigned short* PT   = (unsigned short*)carve((size_t)DD * 256 * 2);     // 64 KB
  int* cnt_vr          = (int*)carve((size_t)N2 * 4);
  int* rp2             = (int*)carve((size_t)(N2 + 1) * 4);
  int* cur2            = (int*)carve((size_t)N2 * 4);
  unsigned* packed     = (unsigned*)carve((size_t)NE * 4);                 // 2.4 MB
  unsigned* omask      = (unsigned*)carve((size_t)NN * 4);                 // 200 KB
  int* bsum            = (int*)carve((size_t)512 * 4);
  int* boff            = (int*)carve((size_t)512 * 4);
  (void)ws_size; (void)in_sizes; (void)n_in; (void)out_size;

  hipMemsetAsync(cnt_vr, 0, (size_t)N2 * 4, stream);
  hipMemsetAsync(omask, 0, (size_t)NN * 4, stream);

  int egrid = (NE + 255) / 256;
  k_hist<<<egrid, 256, 0, stream>>>(ei, et, cnt_vr, omask);
  k_scan1<<<NBS2, 256, 0, stream>>>(cnt_vr, bsum);
  k_scan2<<<1, 512, 0, stream>>>(bsum, boff);
  k_scan3<<<NBS2, 256, 0, stream>>>(cnt_vr, boff, rp2, cur2);
  k_scatter<<<egrid, 256, 0, stream>>>(ei, et, cur2, packed);

  k_xb<<<(NN * (DD / 2) + 255) / 256, 256, 0, stream>>>(node_feat, (unsigned*)xb);
  k_wt2<<<(2 * KY * DD + 255) / 256, 256, 0, stream>>>(rel_w, root_w, WT2);
  k_pt<<<(DD * 256 + 255) / 256, 256, 0, stream>>>(proj_w, PT);

  // layer 1: Y = xb @ W'(l=0); out_h1 = gather(Y) (+root,+bias,relu)
  k_ygemm<<<MGRID * 9, 512, 0, stream>>>(xb, DD, WT2, omask, Y);
  k_aggD<<<NN / 4, 256, 0, stream>>>(Y, packed, rp2, bias,
                                     out + (size_t)NN * DD, Hb, 0);
  // layer 2: Y = h1 @ W'(l=1); out_h2 = gather(Y)
  k_ygemm<<<MGRID * 9, 512, 0, stream>>>(Hb, 256, WT2 + (size_t)KY * DD, omask, Y);
  k_aggD<<<NN / 4, 256, 0, stream>>>(Y, packed, rp2, bias + DD,
                                     out + (size_t)2 * NN * DD, Hb, DD);
  // projection: final = [h1|h2] @ proj_w + proj_b
  k_gemm<<<MGRID, 256, 0, stream>>>(Hb, 256, PT, 256, NN, 256, proj_b, out);
}

// Round 18
// 261.090 us; speedup vs baseline: 1.2707x; 1.2707x over previous
//
#include <hip/hip_runtime.h>
#include <hip/hip_bf16.h>

#define NN 50000
#define NE 600000
#define DD 128
#define RR 8
#define KY 1152   /* Y cols: 8 relations * 128 + root 128 */

#define N2 (NN * RR)                       /* (v,r) segments, v-major */
#define SCHUNK 1024
#define NBS2 ((N2 + SCHUNK - 1) / SCHUNK)  /* 391 */
#define MGRID ((NN + 127) / 128)           /* 391 row-tiles */

typedef __attribute__((ext_vector_type(8))) short short8;
typedef __attribute__((ext_vector_type(4))) float f32x4;
typedef __attribute__((ext_vector_type(4))) unsigned uint4v;

__device__ __forceinline__ unsigned short f2b(float x){
  __hip_bfloat16 h = __float2bfloat16(x);
  return __builtin_bit_cast(unsigned short, h);
}
__device__ __forceinline__ float blo(unsigned u){ return __builtin_bit_cast(float, u << 16); }
__device__ __forceinline__ float bhi(unsigned u){ return __builtin_bit_cast(float, u & 0xFFFF0000u); }
__device__ __forceinline__ unsigned pack2(float a, float b){
  return (unsigned)f2b(a) | ((unsigned)f2b(b) << 16);
}

#define GLDS16(g, l) __builtin_amdgcn_global_load_lds( \
    (const __attribute__((address_space(1))) void*)(g), \
    (__attribute__((address_space(3))) void*)(l), 16, 0, 0)

// ---------------- edge structure build: CSR over v-major (dst, rel) segments ----------------
__global__ __launch_bounds__(256) void k_hist(const int* __restrict__ ei,
                                              const int* __restrict__ et,
                                              int* __restrict__ cnt) {
  int e = blockIdx.x * 256 + threadIdx.x;
  if (e < NE) {
    int dst = ei[NE + e];
    int r = et[e];
    atomicAdd(&cnt[dst * RR + r], 1);
  }
}

__global__ __launch_bounds__(256) void k_scan1(const int* __restrict__ cnt,
                                               int* __restrict__ bsum) {
  int b = blockIdx.x, t = threadIdx.x;
  int base = b * SCHUNK + t * 4;
  int s = 0;
  if (base < N2) {
    int4 v = *(const int4*)&cnt[base];
    s = v.x + v.y + v.z + v.w;
  }
  #pragma unroll
  for (int off = 32; off; off >>= 1) s += __shfl_down(s, off);
  __shared__ int wsum[4];
  int lane = t & 63, wv = t >> 6;
  if (lane == 0) wsum[wv] = s;
  __syncthreads();
  if (t == 0) bsum[b] = wsum[0] + wsum[1] + wsum[2] + wsum[3];
}

__global__ __launch_bounds__(512) void k_scan2(const int* __restrict__ bsum,
                                               int* __restrict__ boff) {
  int t = threadIdx.x, lane = t & 63, wv = t >> 6;
  int v = (t < NBS2) ? bsum[t] : 0;
  int x = v;
  #pragma unroll
  for (int off = 1; off < 64; off <<= 1) {
    int y = __shfl_up(x, off);
    if (lane >= off) x += y;
  }
  __shared__ int wt[8];
  if (lane == 63) wt[wv] = x;
  __syncthreads();
  int woff = 0;
  for (int w = 0; w < wv; w++) woff += wt[w];
  if (t < NBS2) boff[t] = woff + x - v;
}

__global__ __launch_bounds__(256) void k_scan3(const int* __restrict__ cnt,
                                               const int* __restrict__ boff,
                                               int* __restrict__ rp2,
                                               int* __restrict__ cur2) {
  int b = blockIdx.x, t = threadIdx.x;
  int lane = t & 63, wv = t >> 6;
  int base = b * SCHUNK + t * 4;
  int v[4] = {0, 0, 0, 0};
  int s = 0;
  if (base < N2) {
    int4 q = *(const int4*)&cnt[base];
    v[0] = q.x; v[1] = q.y; v[2] = q.z; v[3] = q.w;
    s = q.x + q.y + q.z + q.w;
  }
  int x = s;
  #pragma unroll
  for (int off = 1; off < 64; off <<= 1) {
    int y = __shfl_up(x, off);
    if (lane >= off) x += y;
  }
  __shared__ int wtot[4];
  if (lane == 63) wtot[wv] = x;
  __syncthreads();
  int woff = 0;
  for (int w = 0; w < wv; w++) woff += wtot[w];
  int exc = boff[b] + woff + x - s;
  if (base < N2) {
    #pragma unroll
    for (int j = 0; j < 4; j++) {
      cur2[base + j] = exc;
      rp2[base + j + 1] = exc + v[j];
      exc += v[j];
    }
  }
  if (b == 0 && t == 0) rp2[0] = 0;
}

__global__ __launch_bounds__(256) void k_scatter(const int* __restrict__ ei,
                                                 const int* __restrict__ et,
                                                 int* __restrict__ cur2,
                                                 unsigned* __restrict__ packed) {
  int e = blockIdx.x * 256 + threadIdx.x;
  if (e < NE) {
    int src = ei[e];
    int dst = ei[NE + e];
    int r = et[e];
    int p = atomicAdd(&cur2[dst * RR + r], 1);
    packed[p] = (unsigned)src | ((unsigned)r << 16);   // src < 65536
  }
}

// ---------------- prep: bf16 conversions ----------------
__global__ __launch_bounds__(256) void k_xb(const float* __restrict__ x,
                                            unsigned* __restrict__ xb2) {
  int i = blockIdx.x * 256 + threadIdx.x;
  if (i < NN * (DD / 2)) {
    float2 v = ((const float2*)x)[i];
    xb2[i] = pack2(v.x, v.y);
  }
}

// WT2[l][j][k] bf16, j in [0,1152): j<1024 -> rel_w[l][j>>7][k][j&127], else root_w[l][k][j-1024]
__global__ __launch_bounds__(256) void k_wt2(const float* __restrict__ rel_w,
                                             const float* __restrict__ root_w,
                                             unsigned short* __restrict__ WT2) {
  int idx = blockIdx.x * 256 + threadIdx.x;
  if (idx >= 2 * KY * DD) return;
  int k = idx % DD;
  int j = (idx / DD) % KY;
  int l = idx / (DD * KY);
  float v;
  if (j < RR * DD) v = rel_w[(((size_t)l * RR + (j >> 7)) * DD + k) * DD + (j & 127)];
  else             v = root_w[((size_t)l * DD + k) * DD + (j - RR * DD)];
  WT2[idx] = f2b(v);
}

// PT[n][k] = proj_w[k][n], k<256
__global__ __launch_bounds__(256) void k_pt(const float* __restrict__ proj_w,
                                            unsigned short* __restrict__ PT) {
  int idx = blockIdx.x * 256 + threadIdx.x;
  if (idx >= DD * 256) return;
  int k = idx % 256;
  int n = idx / 256;
  PT[idx] = f2b(proj_w[(size_t)k * DD + n]);
}

// ---------------- Y-GEMM v6: Y[M,1152] = A[M,128] @ W'[128,1152]  (bf16 out) ----------------
// One 128x128 tile per block, 8 waves (64x32 sub-tile each). ONLY A staged in
// LDS (32 KB); strictly m97-ordered: GLDS -> barrier -> (B reg loads + ds_read
// + MFMA). C stored directly as per-lane u16 (no restage, 1 barrier total).
// XCD-grouped rt-major map keeps a row-tile's 9 col-tiles on one XCD.
__global__ __launch_bounds__(512) void k_ygemm(const unsigned short* __restrict__ A, int lda,
                                               const unsigned short* __restrict__ B2, /* [1152][128] */
                                               unsigned short* __restrict__ Y) {
  __shared__ unsigned short smA[128 * 128];   // 32 KB
  int t = threadIdx.x;
  // bijective XCD-grouped mapping (grid = MGRID*9 = 3519)
  const int nb = MGRID * 9, q8 = nb >> 3, r8 = nb & 7;   // 3519, 439, 7
  int xcd = blockIdx.x & 7, idx = blockIdx.x >> 3;
  int w = (xcd < r8 ? xcd * (q8 + 1) : r8 * (q8 + 1) + (xcd - r8) * q8) + idx;
  int rt = w / 9, ct = w % 9;

  int lane = t & 63, wv = t >> 6;             // wv 0..7
  int wm = wv >> 2, wn = wv & 3;              // 2M x 4N wave grid, 64x32 each
  int l15 = lane & 15, lk = lane >> 4;

  // issue A-stage (swizzled source -> linear LDS); nothing else before barrier
  #pragma unroll
  for (int i = 0; i < 4; i++) {
    int f = i * 512 + t;
    int row = f >> 4, cl = f & 15;
    int cg = cl ^ (row & 15);
    int rg = rt * 128 + row; if (rg >= NN) rg = NN - 1;
    GLDS16(A + (size_t)rg * lda + cg * 8, &smA[f * 8]);
  }
  __syncthreads();   // A tile ready

  // B fragments direct from L2 (0.29 MB, hot on this XCD)
  short8 bf[4][2];
  #pragma unroll
  for (int kk = 0; kk < 4; kk++)
    #pragma unroll
    for (int q = 0; q < 2; q++) {
      int rb = ct * 128 + wn * 32 + q * 16 + l15;
      bf[kk][q] = *(const short8*)(B2 + (size_t)rb * DD + (kk * 4 + lk) * 8);
    }

  f32x4 acc[4][2];
  #pragma unroll
  for (int mi = 0; mi < 4; mi++)
    #pragma unroll
    for (int ni = 0; ni < 2; ni++)
      acc[mi][ni] = (f32x4){0.f, 0.f, 0.f, 0.f};

  #pragma unroll
  for (int kk = 0; kk < 4; kk++) {
    short8 af[4];
    int c = kk * 4 + lk;
    #pragma unroll
    for (int q = 0; q < 4; q++) {
      int r = wm * 64 + q * 16 + l15;
      af[q] = *(const short8*)&smA[r * 128 + ((c ^ (r & 15)) << 3)];
    }
    #pragma unroll
    for (int mi = 0; mi < 4; mi++)
      #pragma unroll
      for (int ni = 0; ni < 2; ni++)
        acc[mi][ni] = __builtin_amdgcn_mfma_f32_16x16x32_bf16(af[mi], bf[kk][ni], acc[mi][ni], 0, 0, 0);
  }

  // direct store: per-lane u16 (16-lane 32B segments; L2 merges lines)
  #pragma unroll
  for (int mi = 0; mi < 4; mi++) {
    #pragma unroll
    for (int ni = 0; ni < 2; ni++) {
      int col = ct * 128 + wn * 32 + ni * 16 + l15;
      #pragma unroll
      for (int j = 0; j < 4; j++) {
        int rg = rt * 128 + wm * 64 + mi * 16 + lk * 4 + j;
        if (rg < NN) Y[(size_t)rg * KY + col] = f2b(acc[mi][ni][j]);
      }
    }
  }
}

// ---------------- weighted gather: out[v] = sum_e w_e * Y[src_e, r_e*128:] + Y[v,1024:] + bias ----------------
__global__ __launch_bounds__(256) void k_aggD(const unsigned short* __restrict__ Y,
                                              const unsigned* __restrict__ packed,
                                              const int* __restrict__ rp2,
                                              const float* __restrict__ bias,
                                              float* __restrict__ outf,
                                              unsigned short* __restrict__ hb, int hboff) {
  int v = blockIdx.x * 4 + (threadIdx.x >> 6);
  int lane = threadIdx.x & 63;
  int q = lane >> 4, sub = lane & 15;

  // fenceposts rp2[v*8 .. v*8+8] on lanes 0..8
  int f = 0;
  if (lane <= 8) f = rp2[v * RR + lane];
  int fn = __shfl(f, lane + 1);             // lane l: rp2[v*8+l+1] (l<8 valid)
  int c = fn - f;
  float winv = (lane < 8 && c > 0) ? 1.f / (float)c : 0.f;
  int e0 = __shfl(f, 0), e1 = __shfl(f, 8);

  float acc[8];
  #pragma unroll
  for (int j = 0; j < 8; j++) acc[j] = 0.f;

  // 4 quarter-waves, each owns 16B of the row; 2-deep pipeline on packed[]
  int e = e0 + q;
  unsigned rec = (e < e1) ? packed[e] : 0u;
  while (e < e1) {
    int en = e + 4;
    unsigned rec_next = (en < e1) ? packed[en] : 0u;
    int src = rec & 0xFFFF;
    int r = rec >> 16;
    float w = __shfl(winv, r);
    uint4v u = *(const uint4v*)(Y + (size_t)src * KY + r * DD + sub * 8);
    #pragma unroll
    for (int i = 0; i < 4; i++) {
      acc[2 * i]     += w * blo(u[i]);
      acc[2 * i + 1] += w * bhi(u[i]);
    }
    e = en; rec = rec_next;
  }

  // root term (once, quarter 0)
  if (q == 0) {
    uint4v u = *(const uint4v*)(Y + (size_t)v * KY + RR * DD + sub * 8);
    #pragma unroll
    for (int i = 0; i < 4; i++) {
      acc[2 * i]     += blo(u[i]);
      acc[2 * i + 1] += bhi(u[i]);
    }
  }

  // reduce across quarters
  #pragma unroll
  for (int j = 0; j < 8; j++) {
    acc[j] += __shfl_xor(acc[j], 32);
    acc[j] += __shfl_xor(acc[j], 16);
  }

  if (q == 0) {
    float4 b0 = *(const float4*)&bias[sub * 8];
    float4 b1 = *(const float4*)&bias[sub * 8 + 4];
    float val[8];
    val[0] = fmaxf(acc[0] + b0.x, 0.f); val[1] = fmaxf(acc[1] + b0.y, 0.f);
    val[2] = fmaxf(acc[2] + b0.z, 0.f); val[3] = fmaxf(acc[3] + b0.w, 0.f);
    val[4] = fmaxf(acc[4] + b1.x, 0.f); val[5] = fmaxf(acc[5] + b1.y, 0.f);
    val[6] = fmaxf(acc[6] + b1.z, 0.f); val[7] = fmaxf(acc[7] + b1.w, 0.f);
    float4* of = (float4*)&outf[(size_t)v * DD + sub * 8];
    of[0] = (float4){val[0], val[1], val[2], val[3]};
    of[1] = (float4){val[4], val[5], val[6], val[7]};
    uint4v hv;
    #pragma unroll
    for (int i = 0; i < 4; i++) hv[i] = pack2(val[2 * i], val[2 * i + 1]);
    *(uint4v*)(hb + (size_t)v * 256 + hboff + sub * 8) = hv;
  }
}

// ---------------- bf16 MFMA GEMM (projection): C[M,128] = A[M,K] * BT[128,K]^T + bias ----------------
__global__ __launch_bounds__(256) void k_gemm(const unsigned short* __restrict__ A, int lda,
                                              const unsigned short* __restrict__ BT, int ldb,
                                              int M, int K,
                                              const float* __restrict__ bias,
                                              float* __restrict__ outf) {
  __shared__ unsigned short sA[128 * 64];
  __shared__ unsigned short sB[128 * 64];
  int t = threadIdx.x;
  int bm = blockIdx.x;
  int lane = t & 63, wv = t >> 6;
  int wm = wv >> 1, wn = wv & 1;
  int l15 = lane & 15, lk = lane >> 4;

  f32x4 acc[4][4];
  #pragma unroll
  for (int mi = 0; mi < 4; mi++)
    #pragma unroll
    for (int ni = 0; ni < 4; ni++)
      acc[mi][ni] = (f32x4){0.f, 0.f, 0.f, 0.f};

  int nkt = K >> 6;
  for (int kt = 0; kt < nkt; kt++) {
    #pragma unroll
    for (int i = 0; i < 4; i++) {
      int f = i * 256 + t;
      int row = f >> 3, cl = f & 7;
      int cg = cl ^ (row & 7);
      int rg = bm * 128 + row;
      if (rg >= M) rg = M - 1;
      GLDS16(A + (size_t)rg * lda + kt * 64 + cg * 8, &sA[f * 8]);
    }
    #pragma unroll
    for (int i = 0; i < 4; i++) {
      int f = i * 256 + t;
      int row = f >> 3, cl = f & 7;
      int cg = cl ^ (row & 7);
      GLDS16(BT + (size_t)row * ldb + kt * 64 + cg * 8, &sB[f * 8]);
    }
    __syncthreads();

    short8 af[4][2], bf[4][2];
    #pragma unroll
    for (int mi = 0; mi < 4; mi++) {
      #pragma unroll
      for (int kk = 0; kk < 2; kk++) {
        int r = wm * 64 + mi * 16 + l15;
        int c = kk * 4 + lk;
        af[mi][kk] = *(const short8*)&sA[((r << 3) + (c ^ (r & 7))) << 3];
        int rb = wn * 64 + mi * 16 + l15;
        bf[mi][kk] = *(const short8*)&sB[((rb << 3) + (c ^ (rb & 7))) << 3];
      }
    }
    #pragma unroll
    for (int mi = 0; mi < 4; mi++)
      #pragma unroll
      for (int ni = 0; ni < 4; ni++)
        #pragma unroll
        for (int kk = 0; kk < 2; kk++)
          acc[mi][ni] = __builtin_amdgcn_mfma_f32_16x16x32_bf16(af[mi][kk], bf[ni][kk], acc[mi][ni], 0, 0, 0);
    __syncthreads();
  }

  #pragma unroll
  for (int mi = 0; mi < 4; mi++) {
    #pragma unroll
    for (int ni = 0; ni < 4; ni++) {
      int cg = wn * 64 + ni * 16 + l15;
      float bv = bias[cg];
      #pragma unroll
      for (int j = 0; j < 4; j++) {
        int rg = bm * 128 + wm * 64 + mi * 16 + lk * 4 + j;
        if (rg < M) outf[(size_t)rg * 128 + cg] = acc[mi][ni][j] + bv;
      }
    }
  }
}

// ---------------- launch ----------------
extern "C" void kernel_launch(void* const* d_in, const int* in_sizes, int n_in,
                              void* d_out, int out_size, void* d_ws, size_t ws_size,
                              hipStream_t stream) {
  const float* node_feat = (const float*)d_in[0];
  const int*   ei        = (const int*)d_in[1];
  const int*   et        = (const int*)d_in[2];
  const float* rel_w     = (const float*)d_in[3];
  const float* root_w    = (const float*)d_in[4];
  const float* bias      = (const float*)d_in[5];
  const float* proj_w    = (const float*)d_in[6];
  const float* proj_b    = (const float*)d_in[7];
  float* out = (float*)d_out;

  char* ws = (char*)d_ws;
  size_t off = 0;
  auto carve = [&](size_t bytes) { void* p = ws + off; off = (off + bytes + 255) & ~(size_t)255; return p; };
  unsigned short* Y    = (unsigned short*)carve((size_t)NN * KY * 2);      // 115.2 MB
  unsigned short* Hb   = (unsigned short*)carve((size_t)NN * 256 * 2);     // 25.6 MB [h1|h2] bf16
  unsigned short* xb   = (unsigned short*)carve((size_t)NN * DD * 2);      // 12.8 MB
  unsigned short* WT2  = (unsigned short*)carve((size_t)2 * KY * DD * 2);  // 0.59 MB
  unsigned short* PT   = (unsigned short*)carve((size_t)DD * 256 * 2);     // 64 KB
  int* cnt_vr          = (int*)carve((size_t)N2 * 4);
  int* rp2             = (int*)carve((size_t)(N2 + 1) * 4);
  int* cur2            = (int*)carve((size_t)N2 * 4);
  unsigned* packed     = (unsigned*)carve((size_t)NE * 4);                 // 2.4 MB
  int* bsum            = (int*)carve((size_t)512 * 4);
  int* boff            = (int*)carve((size_t)512 * 4);
  (void)ws_size; (void)in_sizes; (void)n_in; (void)out_size;

  hipMemsetAsync(cnt_vr, 0, (size_t)N2 * 4, stream);

  int egrid = (NE + 255) / 256;
  k_hist<<<egrid, 256, 0, stream>>>(ei, et, cnt_vr);
  k_scan1<<<NBS2, 256, 0, stream>>>(cnt_vr, bsum);
  k_scan2<<<1, 512, 0, stream>>>(bsum, boff);
  k_scan3<<<NBS2, 256, 0, stream>>>(cnt_vr, boff, rp2, cur2);
  k_scatter<<<egrid, 256, 0, stream>>>(ei, et, cur2, packed);

  k_xb<<<(NN * (DD / 2) + 255) / 256, 256, 0, stream>>>(node_feat, (unsigned*)xb);
  k_wt2<<<(2 * KY * DD + 255) / 256, 256, 0, stream>>>(rel_w, root_w, WT2);
  k_pt<<<(DD * 256 + 255) / 256, 256, 0, stream>>>(proj_w, PT);

  // layer 1: Y = xb @ W'(l=0); out_h1 = gather(Y) (+root,+bias,relu)
  k_ygemm<<<MGRID * 9, 512, 0, stream>>>(xb, DD, WT2, Y);
  k_aggD<<<NN / 4, 256, 0, stream>>>(Y, packed, rp2, bias,
                                     out + (size_t)NN * DD, Hb, 0);
  // layer 2: Y = h1 @ W'(l=1); out_h2 = gather(Y)
  k_ygemm<<<MGRID * 9, 512, 0, stream>>>(Hb, 256, WT2 + (size_t)KY * DD, Y);
  k_aggD<<<NN / 4, 256, 0, stream>>>(Y, packed, rp2, bias + DD,
                                     out + (size_t)2 * NN * DD, Hb, DD);
  // projection: final = [h1|h2] @ proj_w + proj_b
  k_gemm<<<MGRID, 256, 0, stream>>>(Hb, 256, PT, 256, NN, 256, proj_b, out);
}

// Round 19
// 259.347 us; speedup vs baseline: 1.2792x; 1.0067x over previous
//
#include <hip/hip_runtime.h>
#include <hip/hip_bf16.h>

#define NN 50000
#define NE 600000
#define DD 128
#define RR 8
#define KY 1152   /* Y cols: 8 relations * 128 + root 128 */

#define N2 (NN * RR)                       /* (v,r) segments, v-major */
#define SCHUNK 1024
#define NBS2 ((N2 + SCHUNK - 1) / SCHUNK)  /* 391 */
#define MGRID ((NN + 127) / 128)           /* 391 row-tiles */
#define PGRID ((NN + 63) / 64)             /* 782 proj row-tiles */

#define NB_XB (NN * (DD / 2) / 256)        /* 12500 */
#define NB_WT (2 * KY * DD / 256)          /* 1152 */
#define NB_PT (DD * 256 / 256)             /* 128 */

typedef __attribute__((ext_vector_type(8))) short short8;
typedef __attribute__((ext_vector_type(4))) float f32x4;
typedef __attribute__((ext_vector_type(4))) unsigned uint4v;

__device__ __forceinline__ unsigned short f2b(float x){
  __hip_bfloat16 h = __float2bfloat16(x);
  return __builtin_bit_cast(unsigned short, h);
}
__device__ __forceinline__ float blo(unsigned u){ return __builtin_bit_cast(float, u << 16); }
__device__ __forceinline__ float bhi(unsigned u){ return __builtin_bit_cast(float, u & 0xFFFF0000u); }
__device__ __forceinline__ unsigned pack2(float a, float b){
  return (unsigned)f2b(a) | ((unsigned)f2b(b) << 16);
}

#define GLDS16(g, l) __builtin_amdgcn_global_load_lds( \
    (const __attribute__((address_space(1))) void*)(g), \
    (__attribute__((address_space(3))) void*)(l), 16, 0, 0)

// ---------------- edge structure build: CSR over v-major (dst, rel) segments ----------------
__global__ __launch_bounds__(256) void k_hist(const int* __restrict__ ei,
                                              const int* __restrict__ et,
                                              int* __restrict__ cnt) {
  int e = blockIdx.x * 256 + threadIdx.x;
  if (e < NE) {
    int dst = ei[NE + e];
    int r = et[e];
    atomicAdd(&cnt[dst * RR + r], 1);
  }
}

__global__ __launch_bounds__(256) void k_scan1(const int* __restrict__ cnt,
                                               int* __restrict__ bsum) {
  int b = blockIdx.x, t = threadIdx.x;
  int base = b * SCHUNK + t * 4;
  int s = 0;
  if (base < N2) {
    int4 v = *(const int4*)&cnt[base];
    s = v.x + v.y + v.z + v.w;
  }
  #pragma unroll
  for (int off = 32; off; off >>= 1) s += __shfl_down(s, off);
  __shared__ int wsum[4];
  int lane = t & 63, wv = t >> 6;
  if (lane == 0) wsum[wv] = s;
  __syncthreads();
  if (t == 0) bsum[b] = wsum[0] + wsum[1] + wsum[2] + wsum[3];
}

__global__ __launch_bounds__(512) void k_scan2(const int* __restrict__ bsum,
                                               int* __restrict__ boff) {
  int t = threadIdx.x, lane = t & 63, wv = t >> 6;
  int v = (t < NBS2) ? bsum[t] : 0;
  int x = v;
  #pragma unroll
  for (int off = 1; off < 64; off <<= 1) {
    int y = __shfl_up(x, off);
    if (lane >= off) x += y;
  }
  __shared__ int wt[8];
  if (lane == 63) wt[wv] = x;
  __syncthreads();
  int woff = 0;
  for (int w = 0; w < wv; w++) woff += wt[w];
  if (t < NBS2) boff[t] = woff + x - v;
}

__global__ __launch_bounds__(256) void k_scan3(const int* __restrict__ cnt,
                                               const int* __restrict__ boff,
                                               int* __restrict__ rp2,
                                               int* __restrict__ cur2) {
  int b = blockIdx.x, t = threadIdx.x;
  int lane = t & 63, wv = t >> 6;
  int base = b * SCHUNK + t * 4;
  int v[4] = {0, 0, 0, 0};
  int s = 0;
  if (base < N2) {
    int4 q = *(const int4*)&cnt[base];
    v[0] = q.x; v[1] = q.y; v[2] = q.z; v[3] = q.w;
    s = q.x + q.y + q.z + q.w;
  }
  int x = s;
  #pragma unroll
  for (int off = 1; off < 64; off <<= 1) {
    int y = __shfl_up(x, off);
    if (lane >= off) x += y;
  }
  __shared__ int wtot[4];
  if (lane == 63) wtot[wv] = x;
  __syncthreads();
  int woff = 0;
  for (int w = 0; w < wv; w++) woff += wtot[w];
  int exc = boff[b] + woff + x - s;
  if (base < N2) {
    #pragma unroll
    for (int j = 0; j < 4; j++) {
      cur2[base + j] = exc;
      rp2[base + j + 1] = exc + v[j];
      exc += v[j];
    }
  }
  if (b == 0 && t == 0) rp2[0] = 0;
}

__global__ __launch_bounds__(256) void k_scatter(const int* __restrict__ ei,
                                                 const int* __restrict__ et,
                                                 int* __restrict__ cur2,
                                                 unsigned* __restrict__ packed) {
  int e = blockIdx.x * 256 + threadIdx.x;
  if (e < NE) {
    int src = ei[e];
    int dst = ei[NE + e];
    int r = et[e];
    int p = atomicAdd(&cur2[dst * RR + r], 1);
    packed[p] = (unsigned)src | ((unsigned)r << 16);   // src < 65536
  }
}

// ---------------- fused prep: xb (bf16 features), WT2, PT ----------------
__global__ __launch_bounds__(256) void k_prep(const float* __restrict__ x, unsigned* __restrict__ xb2,
                                              const float* __restrict__ rel_w, const float* __restrict__ root_w,
                                              unsigned short* __restrict__ WT2,
                                              const float* __restrict__ proj_w, unsigned short* __restrict__ PT) {
  int b = blockIdx.x, t = threadIdx.x;
  if (b < NB_XB) {
    int i = b * 256 + t;
    float2 v = ((const float2*)x)[i];
    xb2[i] = pack2(v.x, v.y);
  } else if (b < NB_XB + NB_WT) {
    int idx = (b - NB_XB) * 256 + t;
    int k = idx % DD;
    int j = (idx / DD) % KY;
    int l = idx / (DD * KY);
    float v;
    if (j < RR * DD) v = rel_w[(((size_t)l * RR + (j >> 7)) * DD + k) * DD + (j & 127)];
    else             v = root_w[((size_t)l * DD + k) * DD + (j - RR * DD)];
    WT2[idx] = f2b(v);
  } else {
    int idx = (b - NB_XB - NB_WT) * 256 + t;
    int k = idx % 256;
    int n = idx / 256;
    PT[idx] = f2b(proj_w[(size_t)k * DD + n]);
  }
}

// ---------------- Y-GEMM v6: Y[M,1152] = A[M,128] @ W'[128,1152]  (bf16 out) ----------------
__global__ __launch_bounds__(512) void k_ygemm(const unsigned short* __restrict__ A, int lda,
                                               const unsigned short* __restrict__ B2, /* [1152][128] */
                                               unsigned short* __restrict__ Y) {
  __shared__ unsigned short smA[128 * 128];   // 32 KB
  int t = threadIdx.x;
  // bijective XCD-grouped mapping (grid = MGRID*9 = 3519)
  const int nb = MGRID * 9, q8 = nb >> 3, r8 = nb & 7;   // 3519, 439, 7
  int xcd = blockIdx.x & 7, idx = blockIdx.x >> 3;
  int w = (xcd < r8 ? xcd * (q8 + 1) : r8 * (q8 + 1) + (xcd - r8) * q8) + idx;
  int rt = w / 9, ct = w % 9;

  int lane = t & 63, wv = t >> 6;             // wv 0..7
  int wm = wv >> 2, wn = wv & 3;              // 2M x 4N wave grid, 64x32 each
  int l15 = lane & 15, lk = lane >> 4;

  #pragma unroll
  for (int i = 0; i < 4; i++) {
    int f = i * 512 + t;
    int row = f >> 4, cl = f & 15;
    int cg = cl ^ (row & 15);
    int rg = rt * 128 + row; if (rg >= NN) rg = NN - 1;
    GLDS16(A + (size_t)rg * lda + cg * 8, &smA[f * 8]);
  }
  __syncthreads();   // A tile ready

  short8 bf[4][2];
  #pragma unroll
  for (int kk = 0; kk < 4; kk++)
    #pragma unroll
    for (int q = 0; q < 2; q++) {
      int rb = ct * 128 + wn * 32 + q * 16 + l15;
      bf[kk][q] = *(const short8*)(B2 + (size_t)rb * DD + (kk * 4 + lk) * 8);
    }

  f32x4 acc[4][2];
  #pragma unroll
  for (int mi = 0; mi < 4; mi++)
    #pragma unroll
    for (int ni = 0; ni < 2; ni++)
      acc[mi][ni] = (f32x4){0.f, 0.f, 0.f, 0.f};

  #pragma unroll
  for (int kk = 0; kk < 4; kk++) {
    short8 af[4];
    int c = kk * 4 + lk;
    #pragma unroll
    for (int q = 0; q < 4; q++) {
      int r = wm * 64 + q * 16 + l15;
      af[q] = *(const short8*)&smA[r * 128 + ((c ^ (r & 15)) << 3)];
    }
    #pragma unroll
    for (int mi = 0; mi < 4; mi++)
      #pragma unroll
      for (int ni = 0; ni < 2; ni++)
        acc[mi][ni] = __builtin_amdgcn_mfma_f32_16x16x32_bf16(af[mi], bf[kk][ni], acc[mi][ni], 0, 0, 0);
  }

  #pragma unroll
  for (int mi = 0; mi < 4; mi++) {
    #pragma unroll
    for (int ni = 0; ni < 2; ni++) {
      int col = ct * 128 + wn * 32 + ni * 16 + l15;
      #pragma unroll
      for (int j = 0; j < 4; j++) {
        int rg = rt * 128 + wm * 64 + mi * 16 + lk * 4 + j;
        if (rg < NN) Y[(size_t)rg * KY + col] = f2b(acc[mi][ni][j]);
      }
    }
  }
}

// ---------------- weighted gather: out[v] = sum_e w_e * Y[src_e, r_e*128:] + Y[v,1024:] + bias ----------------
__global__ __launch_bounds__(256) void k_aggD(const unsigned short* __restrict__ Y,
                                              const unsigned* __restrict__ packed,
                                              const int* __restrict__ rp2,
                                              const float* __restrict__ bias,
                                              float* __restrict__ outf,
                                              unsigned short* __restrict__ hb, int hboff) {
  int v = blockIdx.x * 4 + (threadIdx.x >> 6);
  int lane = threadIdx.x & 63;
  int q = lane >> 4, sub = lane & 15;

  int f = 0;
  if (lane <= 8) f = rp2[v * RR + lane];
  int fn = __shfl(f, lane + 1);
  int c = fn - f;
  float winv = (lane < 8 && c > 0) ? 1.f / (float)c : 0.f;
  int e0 = __shfl(f, 0), e1 = __shfl(f, 8);

  float acc[8];
  #pragma unroll
  for (int j = 0; j < 8; j++) acc[j] = 0.f;

  int e = e0 + q;
  unsigned rec = (e < e1) ? packed[e] : 0u;
  while (e < e1) {
    int en = e + 4;
    unsigned rec_next = (en < e1) ? packed[en] : 0u;
    int src = rec & 0xFFFF;
    int r = rec >> 16;
    float w = __shfl(winv, r);
    uint4v u = *(const uint4v*)(Y + (size_t)src * KY + r * DD + sub * 8);
    #pragma unroll
    for (int i = 0; i < 4; i++) {
      acc[2 * i]     += w * blo(u[i]);
      acc[2 * i + 1] += w * bhi(u[i]);
    }
    e = en; rec = rec_next;
  }

  if (q == 0) {
    uint4v u = *(const uint4v*)(Y + (size_t)v * KY + RR * DD + sub * 8);
    #pragma unroll
    for (int i = 0; i < 4; i++) {
      acc[2 * i]     += blo(u[i]);
      acc[2 * i + 1] += bhi(u[i]);
    }
  }

  #pragma unroll
  for (int j = 0; j < 8; j++) {
    acc[j] += __shfl_xor(acc[j], 32);
    acc[j] += __shfl_xor(acc[j], 16);
  }

  if (q == 0) {
    float4 b0 = *(const float4*)&bias[sub * 8];
    float4 b1 = *(const float4*)&bias[sub * 8 + 4];
    float val[8];
    val[0] = fmaxf(acc[0] + b0.x, 0.f); val[1] = fmaxf(acc[1] + b0.y, 0.f);
    val[2] = fmaxf(acc[2] + b0.z, 0.f); val[3] = fmaxf(acc[3] + b0.w, 0.f);
    val[4] = fmaxf(acc[4] + b1.x, 0.f); val[5] = fmaxf(acc[5] + b1.y, 0.f);
    val[6] = fmaxf(acc[6] + b1.z, 0.f); val[7] = fmaxf(acc[7] + b1.w, 0.f);
    float4* of = (float4*)&outf[(size_t)v * DD + sub * 8];
    of[0] = (float4){val[0], val[1], val[2], val[3]};
    of[1] = (float4){val[4], val[5], val[6], val[7]};
    uint4v hv;
    #pragma unroll
    for (int i = 0; i < 4; i++) hv[i] = pack2(val[2 * i], val[2 * i + 1]);
    *(uint4v*)(hb + (size_t)v * 256 + hboff + sub * 8) = hv;
  }
}

// ---------------- projection GEMM (v6-style): out[M,128] = Hb[M,256] @ PT[128,256]^T + pb ----------------
// 64-row x 128-col tile per 256-thr block (grid=782). A staged once (32 KB,
// swizzled); PT fragments in regs after single barrier; K=256 in 8 MFMA steps;
// direct fp32 stores (4 rows x 64B segments per inst).
__global__ __launch_bounds__(256) void k_proj(const unsigned short* __restrict__ Hb,
                                              const unsigned short* __restrict__ PT,
                                              const float* __restrict__ pb,
                                              float* __restrict__ outf) {
  __shared__ unsigned short smA[64 * 256];    // 32 KB
  int t = threadIdx.x;
  int rt = blockIdx.x;                        // 0..781
  int lane = t & 63, wn = t >> 6;             // 4 waves, 1M x 4N (32 cols each)
  int l15 = lane & 15, lk = lane >> 4;

  // stage A tile [64 rows][256 k], source-side swizzle (32 chunks/row)
  #pragma unroll
  for (int i = 0; i < 8; i++) {
    int f = i * 256 + t;
    int row = f >> 5, cl = f & 31;
    int cg = cl ^ (row & 15);
    int rg = rt * 64 + row; if (rg >= NN) rg = NN - 1;
    GLDS16(Hb + (size_t)rg * 256 + cg * 8, &smA[f * 8]);
  }
  __syncthreads();

  // B fragments from L2 (PT = 64 KB, hot)
  short8 bf[8][2];
  #pragma unroll
  for (int kk = 0; kk < 8; kk++)
    #pragma unroll
    for (int q = 0; q < 2; q++) {
      int rb = wn * 32 + q * 16 + l15;
      bf[kk][q] = *(const short8*)(PT + (size_t)rb * 256 + (kk * 4 + lk) * 8);
    }

  f32x4 acc[4][2];
  #pragma unroll
  for (int mi = 0; mi < 4; mi++)
    #pragma unroll
    for (int ni = 0; ni < 2; ni++)
      acc[mi][ni] = (f32x4){0.f, 0.f, 0.f, 0.f};

  #pragma unroll
  for (int kk = 0; kk < 8; kk++) {
    short8 af[4];
    int c = kk * 4 + lk;                      // 0..31
    #pragma unroll
    for (int q = 0; q < 4; q++) {
      int r = q * 16 + l15;                   // 0..63
      af[q] = *(const short8*)&smA[r * 256 + ((c ^ (r & 15)) << 3)];
    }
    #pragma unroll
    for (int mi = 0; mi < 4; mi++)
      #pragma unroll
      for (int ni = 0; ni < 2; ni++)
        acc[mi][ni] = __builtin_amdgcn_mfma_f32_16x16x32_bf16(af[mi], bf[kk][ni], acc[mi][ni], 0, 0, 0);
  }

  #pragma unroll
  for (int mi = 0; mi < 4; mi++) {
    #pragma unroll
    for (int ni = 0; ni < 2; ni++) {
      int col = wn * 32 + ni * 16 + l15;
      float bv = pb[col];
      #pragma unroll
      for (int j = 0; j < 4; j++) {
        int rg = rt * 64 + mi * 16 + lk * 4 + j;
        if (rg < NN) outf[(size_t)rg * 128 + col] = acc[mi][ni][j] + bv;
      }
    }
  }
}

// ---------------- launch ----------------
extern "C" void kernel_launch(void* const* d_in, const int* in_sizes, int n_in,
                              void* d_out, int out_size, void* d_ws, size_t ws_size,
                              hipStream_t stream) {
  const float* node_feat = (const float*)d_in[0];
  const int*   ei        = (const int*)d_in[1];
  const int*   et        = (const int*)d_in[2];
  const float* rel_w     = (const float*)d_in[3];
  const float* root_w    = (const float*)d_in[4];
  const float* bias      = (const float*)d_in[5];
  const float* proj_w    = (const float*)d_in[6];
  const float* proj_b    = (const float*)d_in[7];
  float* out = (float*)d_out;

  char* ws = (char*)d_ws;
  size_t off = 0;
  auto carve = [&](size_t bytes) { void* p = ws + off; off = (off + bytes + 255) & ~(size_t)255; return p; };
  unsigned short* Y    = (unsigned short*)carve((size_t)NN * KY * 2);      // 115.2 MB
  unsigned short* Hb   = (unsigned short*)carve((size_t)NN * 256 * 2);     // 25.6 MB [h1|h2] bf16
  unsigned short* xb   = (unsigned short*)carve((size_t)NN * DD * 2);      // 12.8 MB
  unsigned short* WT2  = (unsigned short*)carve((size_t)2 * KY * DD * 2);  // 0.59 MB
  unsigned short* PT   = (unsigned short*)carve((size_t)DD * 256 * 2);     // 64 KB
  int* cnt_vr          = (int*)carve((size_t)N2 * 4);
  int* rp2             = (int*)carve((size_t)(N2 + 1) * 4);
  int* cur2            = (int*)carve((size_t)N2 * 4);
  unsigned* packed     = (unsigned*)carve((size_t)NE * 4);                 // 2.4 MB
  int* bsum            = (int*)carve((size_t)512 * 4);
  int* boff            = (int*)carve((size_t)512 * 4);
  (void)ws_size; (void)in_sizes; (void)n_in; (void)out_size;

  hipMemsetAsync(cnt_vr, 0, (size_t)N2 * 4, stream);

  int egrid = (NE + 255) / 256;
  k_hist<<<egrid, 256, 0, stream>>>(ei, et, cnt_vr);
  k_scan1<<<NBS2, 256, 0, stream>>>(cnt_vr, bsum);
  k_scan2<<<1, 512, 0, stream>>>(bsum, boff);
  k_scan3<<<NBS2, 256, 0, stream>>>(cnt_vr, boff, rp2, cur2);
  k_scatter<<<egrid, 256, 0, stream>>>(ei, et, cur2, packed);

  k_prep<<<NB_XB + NB_WT + NB_PT, 256, 0, stream>>>(node_feat, (unsigned*)xb,
                                                    rel_w, root_w, WT2, proj_w, PT);

  // layer 1: Y = xb @ W'(l=0); out_h1 = gather(Y) (+root,+bias,relu)
  k_ygemm<<<MGRID * 9, 512, 0, stream>>>(xb, DD, WT2, Y);
  k_aggD<<<NN / 4, 256, 0, stream>>>(Y, packed, rp2, bias,
                                     out + (size_t)NN * DD, Hb, 0);
  // layer 2: Y = h1 @ W'(l=1); out_h2 = gather(Y)
  k_ygemm<<<MGRID * 9, 512, 0, stream>>>(Hb, 256, WT2 + (size_t)KY * DD, Y);
  k_aggD<<<NN / 4, 256, 0, stream>>>(Y, packed, rp2, bias + DD,
                                     out + (size_t)2 * NN * DD, Hb, DD);
  // projection: final = [h1|h2] @ proj_w + proj_b
  k_proj<<<PGRID, 256, 0, stream>>>(Hb, PT, proj_b, out);
}